// Round 1
// baseline (910.999 us; speedup 1.0000x reference)
//
#include <hip/hip_runtime.h>

#define NN 50000
#define NHEADS 16
#define NGRAPH 128
#define NEDGE 800000
#define NEP (NEDGE + NN)

typedef float4 f4;

// ---------------- CSR build ----------------

__global__ __launch_bounds__(256) void k_hist(const int* __restrict__ ei, int* __restrict__ counts) {
  int i = blockIdx.x * 256 + threadIdx.x;
  if (i >= NEP) return;
  int d = (i < NEDGE) ? ei[NEDGE + i] : (i - NEDGE);
  atomicAdd(&counts[d], 1);
}

__global__ __launch_bounds__(256) void k_scan1(const int* __restrict__ counts, int* __restrict__ row_off, int* __restrict__ blk_tot) {
  __shared__ int buf[256];
  int t = threadIdx.x;
  int i = blockIdx.x * 256 + t;
  int v = (i < NN) ? counts[i] : 0;
  buf[t] = v;
  __syncthreads();
  for (int off = 1; off < 256; off <<= 1) {
    int y = (t >= off) ? buf[t - off] : 0;
    __syncthreads();
    buf[t] += y;
    __syncthreads();
  }
  if (i < NN) row_off[i] = buf[t] - v;   // exclusive within block
  if (t == 255) blk_tot[blockIdx.x] = buf[255];
}

__global__ __launch_bounds__(256) void k_scan2(const int* __restrict__ blk_tot, int* __restrict__ blk_off, int* __restrict__ row_off, int nb) {
  __shared__ int buf[256];
  int t = threadIdx.x;
  int v = (t < nb) ? blk_tot[t] : 0;
  buf[t] = v;
  __syncthreads();
  for (int off = 1; off < 256; off <<= 1) {
    int y = (t >= off) ? buf[t - off] : 0;
    __syncthreads();
    buf[t] += y;
    __syncthreads();
  }
  if (t < nb) blk_off[t] = buf[t] - v;   // exclusive block offsets
  if (t == 255) row_off[NN] = buf[255];  // total == NEP
}

__global__ __launch_bounds__(256) void k_scan3(int* __restrict__ row_off, const int* __restrict__ blk_off) {
  int i = blockIdx.x * 256 + threadIdx.x;
  if (i < NN) row_off[i] += blk_off[blockIdx.x];
}

__global__ __launch_bounds__(256) void k_scatter(const int* __restrict__ ei, int* __restrict__ cursor, int* __restrict__ col) {
  int i = blockIdx.x * 256 + threadIdx.x;
  if (i >= NEP) return;
  int s, d;
  if (i < NEDGE) { s = ei[i]; d = ei[NEDGE + i]; }
  else { s = d = i - NEDGE; }
  int pos = atomicAdd(&cursor[d], 1);
  col[pos] = s;
}

// ---------------- GEMM: H = X @ W   (X [NN,128], W [128,128]) ----------------

__global__ __launch_bounds__(256) void k_gemm(const float* __restrict__ X, const float* __restrict__ W, float* __restrict__ H) {
  __shared__ float Ws[128 * 128];   // 64 KB
  __shared__ float Xs[64 * 128];    // 32 KB
  int t = threadIdx.x;
  int r0 = blockIdx.x * 64;
  const f4* W4 = (const f4*)W;
  f4* Ws4 = (f4*)Ws;
#pragma unroll
  for (int i = 0; i < 16; ++i) Ws4[t + 256 * i] = W4[t + 256 * i];
  const f4* X4 = (const f4*)X;
  f4* Xs4 = (f4*)Xs;
#pragma unroll
  for (int i = 0; i < 8; ++i) {
    int idx = t + 256 * i;                 // float4 index: row = idx>>5, c4 = idx&31
    int row = r0 + (idx >> 5);
    Xs4[idx] = (row < NN) ? X4[(size_t)row * 32 + (idx & 31)] : make_float4(0.f, 0.f, 0.f, 0.f);
  }
  __syncthreads();
  int tr = t >> 5, tc = t & 31;            // 8 row-groups x 32 col-groups
  f4 acc[8];
#pragma unroll
  for (int i = 0; i < 8; ++i) acc[i] = make_float4(0.f, 0.f, 0.f, 0.f);
  for (int k = 0; k < 128; ++k) {
    f4 w = Ws4[k * 32 + tc];
#pragma unroll
    for (int i = 0; i < 8; ++i) {
      float xv = Xs[(tr * 8 + i) * 128 + k];
      acc[i].x += xv * w.x; acc[i].y += xv * w.y; acc[i].z += xv * w.z; acc[i].w += xv * w.w;
    }
  }
  f4* H4 = (f4*)H;
#pragma unroll
  for (int i = 0; i < 8; ++i) {
    int row = r0 + tr * 8 + i;
    if (row < NN) H4[(size_t)row * 32 + tc] = acc[i];
  }
}

// ---------------- attention coefficients: a_s[n,h], a_d[n,h] ----------------

__global__ __launch_bounds__(256) void k_coef(const float* __restrict__ H, const float* __restrict__ asrc,
                                              const float* __restrict__ adst, float* __restrict__ As, float* __restrict__ Ad) {
  int idx = blockIdx.x * 256 + threadIdx.x;
  if (idx >= NN * NHEADS) return;
  int n = idx >> 4, hd = idx & 15;
  const f4* h4 = (const f4*)(H + (size_t)n * 128 + hd * 8);
  f4 h0 = h4[0], h1 = h4[1];
  const f4* s4 = (const f4*)(asrc + hd * 8);
  const f4* d4 = (const f4*)(adst + hd * 8);
  f4 sa = s4[0], sb = s4[1], da = d4[0], db = d4[1];
  As[idx] = h0.x * sa.x + h0.y * sa.y + h0.z * sa.z + h0.w * sa.w
          + h1.x * sb.x + h1.y * sb.y + h1.z * sb.z + h1.w * sb.w;
  Ad[idx] = h0.x * da.x + h0.y * da.y + h0.z * da.z + h0.w * da.w
          + h1.x * db.x + h1.y * db.y + h1.z * db.z + h1.w * db.w;
}

// ---------------- per-node softmax-attention aggregation (1 wave per node) ----------------

__global__ __launch_bounds__(256) void k_agg(const float* __restrict__ H, const float* __restrict__ As, const float* __restrict__ Ad,
                                             const int* __restrict__ row_off, const int* __restrict__ col,
                                             const float* __restrict__ bias, float* __restrict__ Agg) {
  int n = blockIdx.x * 4 + (threadIdx.x >> 6);
  int lane = threadIdx.x & 63;
  if (n >= NN) return;
  int e0 = row_off[n], e1 = row_off[n + 1];

  // pass 1: per-head max.  lane handles head (lane&15), edge stride 4
  int hm = lane & 15;
  float adm = Ad[n * 16 + hm];
  float mx = -1e30f;
  for (int j = e0 + (lane >> 4); j < e1; j += 4) {
    int s = col[j];
    float e = As[s * 16 + hm] + adm;
    e = (e > 0.f) ? e : 0.2f * e;
    mx = fmaxf(mx, e);
  }
  mx = fmaxf(mx, __shfl_xor(mx, 16));
  mx = fmaxf(mx, __shfl_xor(mx, 32));   // lane l now holds max of head (l&15)

  // pass 2: lane owns channels lane and lane+64 (heads lane>>3 and 8+(lane>>3))
  int h1 = lane >> 3, h2 = 8 + (lane >> 3);
  float m1 = __shfl(mx, h1), m2 = __shfl(mx, h2);
  float ad1 = Ad[n * 16 + h1], ad2 = Ad[n * 16 + h2];
  float den1 = 0.f, den2 = 0.f, acc1 = 0.f, acc2 = 0.f;
  for (int j = e0; j < e1; ++j) {
    int s = col[j];
    float e1v = As[s * 16 + h1] + ad1; e1v = (e1v > 0.f) ? e1v : 0.2f * e1v;
    float e2v = As[s * 16 + h2] + ad2; e2v = (e2v > 0.f) ? e2v : 0.2f * e2v;
    float x1 = __expf(e1v - m1), x2 = __expf(e2v - m2);
    den1 += x1; den2 += x2;
    const float* hrow = H + (size_t)s * 128;
    acc1 += x1 * hrow[lane];
    acc2 += x2 * hrow[64 + lane];
  }
  Agg[(size_t)n * 128 + lane]      = acc1 / (den1 + 1e-16f) + bias[lane];
  Agg[(size_t)n * 128 + 64 + lane] = acc2 / (den2 + 1e-16f) + bias[64 + lane];
}

// ---------------- BatchNorm (training-mode, biased var) + ReLU ----------------

__global__ __launch_bounds__(256) void k_bnreduce(const float* __restrict__ V, float* __restrict__ acc) {
  int t = threadIdx.x;
  int c = t & 127, half = t >> 7;
  float s = 0.f, s2 = 0.f;
  for (int r = blockIdx.x * 2 + half; r < NN; r += 512) {
    float v = V[(size_t)r * 128 + c];
    s += v; s2 += v * v;
  }
  __shared__ float buf[256];
  buf[t] = s; __syncthreads();
  if (t < 128) atomicAdd(&acc[c], buf[t] + buf[t + 128]);
  __syncthreads();
  buf[t] = s2; __syncthreads();
  if (t < 128) atomicAdd(&acc[128 + c], buf[t] + buf[t + 128]);
}

__global__ __launch_bounds__(128) void k_bnfin(const float* __restrict__ acc, const float* __restrict__ gam,
                                               const float* __restrict__ bet, float* __restrict__ sc) {
  int c = threadIdx.x;
  float mean = acc[c] * (1.f / NN);
  float var = acc[128 + c] * (1.f / NN) - mean * mean;
  var = fmaxf(var, 0.f);
  float s = gam[c] * rsqrtf(var + 1e-5f);
  sc[c] = s;
  sc[128 + c] = bet[c] - mean * s;
}

__global__ __launch_bounds__(256) void k_bnapply(float* __restrict__ V, const float* __restrict__ sc) {
  int idx = blockIdx.x * 256 + threadIdx.x;   // float4 index, total NN*32
  f4* V4 = (f4*)V;
  const f4* sc4 = (const f4*)sc;
  int c4 = idx & 31;
  f4 v = V4[idx];
  f4 s = sc4[c4], sh = sc4[32 + c4];
  v.x = fmaxf(v.x * s.x + sh.x, 0.f);
  v.y = fmaxf(v.y * s.y + sh.y, 0.f);
  v.z = fmaxf(v.z * s.z + sh.z, 0.f);
  v.w = fmaxf(v.w * s.w + sh.w, 0.f);
  V4[idx] = v;
}

// ---------------- pooling + final linear + BN ----------------

__global__ __launch_bounds__(256) void k_pool(const float* __restrict__ V, const int* __restrict__ batch, float* __restrict__ pooled) {
  int t = threadIdx.x;
  int c = t & 127, half = t >> 7;
  int r0 = blockIdx.x * 256;
  int rend = (r0 + 256 < NN) ? (r0 + 256) : NN;
  float s = 0.f; int cur = -1;
  for (int r = r0 + half; r < rend; r += 2) {
    int g = batch[r];
    if (g != cur) {
      if (cur >= 0) atomicAdd(&pooled[cur * 128 + c], s);
      cur = g; s = 0.f;
    }
    s += V[(size_t)r * 128 + c];
  }
  if (cur >= 0) atomicAdd(&pooled[cur * 128 + c], s);
}

__global__ __launch_bounds__(256) void k_cnt(const int* __restrict__ batch, int* __restrict__ gcnt) {
  int i = blockIdx.x * 256 + threadIdx.x;
  if (i < NN) atomicAdd(&gcnt[batch[i]], 1);
}

__global__ __launch_bounds__(256) void k_final(const float* __restrict__ pooled, const int* __restrict__ gcnt,
                                               const float* __restrict__ Wl, const float* __restrict__ bl,
                                               const float* __restrict__ g4, const float* __restrict__ b4,
                                               float* __restrict__ out) {
  int t = threadIdx.x;
  int g = t >> 1, cls = t & 1;
  float cnt = fmaxf((float)gcnt[g], 1.f);
  float inv = 1.f / cnt;
  float z = bl[cls];
  for (int f = 0; f < 128; ++f) {
    float ps = pooled[g * 128 + f];
    z += ps * inv * Wl[f * 2 + cls] + ps * Wl[(128 + f) * 2 + cls];
  }
  __shared__ float zs[256];
  __shared__ float st[4];
  zs[t] = z;
  __syncthreads();
  if (t < 2) {
    float s = 0.f, s2 = 0.f;
    for (int gg = 0; gg < 128; ++gg) { float v = zs[gg * 2 + t]; s += v; s2 += v * v; }
    float mean = s * (1.f / 128.f);
    float var = s2 * (1.f / 128.f) - mean * mean;
    var = fmaxf(var, 0.f);
    float sc = g4[t] * rsqrtf(var + 1e-5f);
    st[t] = sc; st[2 + t] = b4[t] - mean * sc;
  }
  __syncthreads();
  out[t] = zs[t] * st[cls] + st[2 + cls];
}

// ---------------- host launcher ----------------

extern "C" void kernel_launch(void* const* d_in, const int* in_sizes, int n_in,
                              void* d_out, int out_size, void* d_ws, size_t ws_size,
                              hipStream_t stream) {
  const float* x     = (const float*)d_in[0];
  const int*   ei    = (const int*)d_in[1];
  const int*   batch = (const int*)d_in[2];
  const float* W[3]    = {(const float*)d_in[3],  (const float*)d_in[9],  (const float*)d_in[15]};
  const float* bias[3] = {(const float*)d_in[4],  (const float*)d_in[10], (const float*)d_in[16]};
  const float* asrc[3] = {(const float*)d_in[5],  (const float*)d_in[11], (const float*)d_in[17]};
  const float* adst[3] = {(const float*)d_in[6],  (const float*)d_in[12], (const float*)d_in[18]};
  const float* gam[3]  = {(const float*)d_in[7],  (const float*)d_in[13], (const float*)d_in[19]};
  const float* bet[3]  = {(const float*)d_in[8],  (const float*)d_in[14], (const float*)d_in[20]};
  const float* Wl    = (const float*)d_in[21];
  const float* bl    = (const float*)d_in[22];
  const float* g4    = (const float*)d_in[23];
  const float* beta4 = (const float*)d_in[24];

  char* ws = (char*)d_ws;
  size_t off = 0;
  auto alloc = [&](size_t bytes) -> void* {
    void* p = (void*)(ws + off);
    off += (bytes + 255) & ~(size_t)255;
    return p;
  };

  int* counts   = (int*)alloc((size_t)NN * 4);
  int* row_off  = (int*)alloc((size_t)(NN + 1) * 4);
  int* cursor   = (int*)alloc((size_t)NN * 4);
  int* col      = (int*)alloc((size_t)NEP * 4);
  int* blk_tot  = (int*)alloc(256 * 4);
  int* blk_off  = (int*)alloc(256 * 4);
  float* bufA   = (float*)alloc((size_t)NN * 128 * 4);
  float* bufB   = (float*)alloc((size_t)NN * 128 * 4);
  float* As     = (float*)alloc((size_t)NN * 16 * 4);
  float* Ad     = (float*)alloc((size_t)NN * 16 * 4);
  float* bn_acc = (float*)alloc(256 * 4);
  float* bn_sc  = (float*)alloc(256 * 4);
  float* pooled = (float*)alloc((size_t)(NGRAPH * 128 + NGRAPH) * 4);  // pooled + gcnt contiguous
  int* gcnt     = (int*)(pooled + NGRAPH * 128);

  // CSR build (identical for all 3 layers)
  hipMemsetAsync(counts, 0, (size_t)NN * 4, stream);
  k_hist<<<(NEP + 255) / 256, 256, 0, stream>>>(ei, counts);
  k_scan1<<<(NN + 255) / 256, 256, 0, stream>>>(counts, row_off, blk_tot);
  k_scan2<<<1, 256, 0, stream>>>(blk_tot, blk_off, row_off, (NN + 255) / 256);
  k_scan3<<<(NN + 255) / 256, 256, 0, stream>>>(row_off, blk_off);
  hipMemcpyAsync(cursor, row_off, (size_t)NN * 4, hipMemcpyDeviceToDevice, stream);
  k_scatter<<<(NEP + 255) / 256, 256, 0, stream>>>(ei, cursor, col);

  hipMemsetAsync(pooled, 0, (size_t)(NGRAPH * 128 + NGRAPH) * 4, stream);

  const float* xin = x;
  float* U = bufA;   // h buffer
  float* V = bufB;   // agg / layer-output buffer
  for (int L = 0; L < 3; ++L) {
    k_gemm<<<(NN + 63) / 64, 256, 0, stream>>>(xin, W[L], U);
    k_coef<<<(NN * 16) / 256, 256, 0, stream>>>(U, asrc[L], adst[L], As, Ad);
    k_agg<<<NN / 4, 256, 0, stream>>>(U, As, Ad, row_off, col, bias[L], V);
    hipMemsetAsync(bn_acc, 0, 256 * 4, stream);
    k_bnreduce<<<256, 256, 0, stream>>>(V, bn_acc);
    k_bnfin<<<1, 128, 0, stream>>>(bn_acc, gam[L], bet[L], bn_sc);
    k_bnapply<<<(NN * 32) / 256, 256, 0, stream>>>(V, bn_sc);
    xin = V;  // layer output is next layer's input; U is free to reuse
  }

  k_pool<<<(NN + 255) / 256, 256, 0, stream>>>(V, batch, pooled);
  k_cnt<<<(NN + 255) / 256, 256, 0, stream>>>(batch, gcnt);
  k_final<<<1, 256, 0, stream>>>(pooled, gcnt, Wl, bl, g4, beta4, (float*)d_out);
}

// Round 2
// 608.406 us; speedup vs baseline: 1.4974x; 1.4974x over previous
//
#include <hip/hip_runtime.h>

#define NN 50000
#define NHEADS 16
#define NGRAPH 128
#define NEDGE 800000
#define NEP (NEDGE + NN)

typedef float4 f4;
typedef __attribute__((ext_vector_type(4))) float f32x4;
typedef __attribute__((ext_vector_type(8))) short s8;   // 8 bf16 (4 VGPRs)

__device__ inline unsigned short f2b(float f) {
  union { float f; unsigned u; } v; v.f = f;
  unsigned r = v.u + 0x7FFFu + ((v.u >> 16) & 1u);   // RNE
  return (unsigned short)(r >> 16);
}
__device__ inline float b2f(unsigned u16) {          // low 16 bits = bf16
  union { unsigned u; float f; } v; v.u = u16 << 16;
  return v.f;
}

// ---------------- CSR build ----------------

__global__ __launch_bounds__(256) void k_hist(const int* __restrict__ ei, int* __restrict__ counts) {
  int i = blockIdx.x * 256 + threadIdx.x;
  if (i >= NEP) return;
  int d = (i < NEDGE) ? ei[NEDGE + i] : (i - NEDGE);
  atomicAdd(&counts[d], 1);
}

__global__ __launch_bounds__(256) void k_scan1(const int* __restrict__ counts, int* __restrict__ row_off, int* __restrict__ blk_tot) {
  __shared__ int buf[256];
  int t = threadIdx.x;
  int i = blockIdx.x * 256 + t;
  int v = (i < NN) ? counts[i] : 0;
  buf[t] = v;
  __syncthreads();
  for (int off = 1; off < 256; off <<= 1) {
    int y = (t >= off) ? buf[t - off] : 0;
    __syncthreads();
    buf[t] += y;
    __syncthreads();
  }
  if (i < NN) row_off[i] = buf[t] - v;
  if (t == 255) blk_tot[blockIdx.x] = buf[255];
}

__global__ __launch_bounds__(256) void k_scan2(const int* __restrict__ blk_tot, int* __restrict__ blk_off, int* __restrict__ row_off, int nb) {
  __shared__ int buf[256];
  int t = threadIdx.x;
  int v = (t < nb) ? blk_tot[t] : 0;
  buf[t] = v;
  __syncthreads();
  for (int off = 1; off < 256; off <<= 1) {
    int y = (t >= off) ? buf[t - off] : 0;
    __syncthreads();
    buf[t] += y;
    __syncthreads();
  }
  if (t < nb) blk_off[t] = buf[t] - v;
  if (t == 255) row_off[NN] = buf[255];
}

__global__ __launch_bounds__(256) void k_scan3(int* __restrict__ row_off, const int* __restrict__ blk_off) {
  int i = blockIdx.x * 256 + threadIdx.x;
  if (i < NN) row_off[i] += blk_off[blockIdx.x];
}

__global__ __launch_bounds__(256) void k_scatter(const int* __restrict__ ei, int* __restrict__ cursor, int* __restrict__ col) {
  int i = blockIdx.x * 256 + threadIdx.x;
  if (i >= NEP) return;
  int s, d;
  if (i < NEDGE) { s = ei[i]; d = ei[NEDGE + i]; }
  else { s = d = i - NEDGE; }
  int pos = atomicAdd(&cursor[d], 1);
  col[pos] = s;
}

// ---------------- fp32 -> bf16 cast (x -> Xb) ----------------

__global__ __launch_bounds__(256) void k_cast(const float* __restrict__ X, unsigned short* __restrict__ Xb, int total8) {
  int i = blockIdx.x * 256 + threadIdx.x;      // 8 elems per thread
  if (i >= total8) return;
  const f4* X4 = (const f4*)X;
  f4 a = X4[2 * i], b = X4[2 * i + 1];
  uint4 o;
  o.x = (unsigned)f2b(a.x) | ((unsigned)f2b(a.y) << 16);
  o.y = (unsigned)f2b(a.z) | ((unsigned)f2b(a.w) << 16);
  o.z = (unsigned)f2b(b.x) | ((unsigned)f2b(b.y) << 16);
  o.w = (unsigned)f2b(b.z) | ((unsigned)f2b(b.w) << 16);
  ((uint4*)Xb)[i] = o;
}

// ---------------- W -> W^T bf16 for all 3 layers ----------------

__global__ __launch_bounds__(256) void k_wt(const float* __restrict__ W0, const float* __restrict__ W1, const float* __restrict__ W2,
                                            unsigned short* __restrict__ T0, unsigned short* __restrict__ T1, unsigned short* __restrict__ T2) {
  int idx = blockIdx.x * 256 + threadIdx.x;    // 3 * 16384
  int L = idx >> 14, r = idx & 16383;
  int n = r >> 7, k = r & 127;
  const float* W = (L == 0) ? W0 : (L == 1) ? W1 : W2;
  unsigned short* T = (L == 0) ? T0 : (L == 1) ? T1 : T2;
  T[n * 128 + k] = f2b(W[k * 128 + n]);
}

// ---------------- GEMM: Hb = bf16( Xb @ W )  via MFMA, no LDS ----------------
// Xb [NN,128] bf16 row-major; Wt [128n][128k] bf16 (W transposed); Hb [NN,128] bf16.
// Wt is 32KB -> L2-resident, read directly from global by every block.

__global__ __launch_bounds__(256) void k_gemm(const unsigned short* __restrict__ Xb, const unsigned short* __restrict__ Wt,
                                              unsigned short* __restrict__ Hb) {
  int w = threadIdx.x >> 6, l = threadIdx.x & 63;
  int r0 = blockIdx.x * 128 + w * 32;          // this wave: rows r0..r0+31, all 128 cols
  int lr = l & 15, lg = l >> 4;                // fragment row/col index, k-group
  f32x4 acc[2][8];
#pragma unroll
  for (int m = 0; m < 2; ++m)
#pragma unroll
    for (int n = 0; n < 8; ++n) acc[m][n] = (f32x4){0.f, 0.f, 0.f, 0.f};

#pragma unroll
  for (int ks = 0; ks < 4; ++ks) {
    int koff = ks * 32 + lg * 8;
    s8 a[2];
#pragma unroll
    for (int m = 0; m < 2; ++m) {
      int row = r0 + m * 16 + lr;
      row = (row < NN) ? row : (NN - 1);
      a[m] = *(const s8*)(Xb + (size_t)row * 128 + koff);
    }
    s8 b[8];
#pragma unroll
    for (int n = 0; n < 8; ++n)
      b[n] = *(const s8*)(Wt + (size_t)(n * 16 + lr) * 128 + koff);
#pragma unroll
    for (int m = 0; m < 2; ++m)
#pragma unroll
      for (int n = 0; n < 8; ++n)
        acc[m][n] = __builtin_amdgcn_mfma_f32_16x16x32_bf16(a[m], b[n], acc[m][n], 0, 0, 0);
  }

  // C/D layout: col = lane&15, row = (lane>>4)*4 + reg   [verified m89/m91]
#pragma unroll
  for (int m = 0; m < 2; ++m) {
    int rowb = r0 + m * 16 + lg * 4;
#pragma unroll
    for (int n = 0; n < 8; ++n) {
      int colb = n * 16 + lr;
#pragma unroll
      for (int reg = 0; reg < 4; ++reg) {
        int row = rowb + reg;
        if (row < NN) Hb[(size_t)row * 128 + colb] = f2b(acc[m][n][reg]);
      }
    }
  }
}

// ---------------- attention coefficients from bf16 H ----------------

__global__ __launch_bounds__(256) void k_coef(const unsigned short* __restrict__ Hb, const float* __restrict__ asrc,
                                              const float* __restrict__ adst, float* __restrict__ As, float* __restrict__ Ad) {
  int idx = blockIdx.x * 256 + threadIdx.x;
  if (idx >= NN * NHEADS) return;
  int n = idx >> 4, hd = idx & 15;
  uint4 hv = *(const uint4*)(Hb + (size_t)n * 128 + hd * 8);
  float h0 = b2f(hv.x & 0xffff), h1 = b2f(hv.x >> 16);
  float h2 = b2f(hv.y & 0xffff), h3 = b2f(hv.y >> 16);
  float h4 = b2f(hv.z & 0xffff), h5 = b2f(hv.z >> 16);
  float h6 = b2f(hv.w & 0xffff), h7 = b2f(hv.w >> 16);
  const f4* s4 = (const f4*)(asrc + hd * 8);
  const f4* d4 = (const f4*)(adst + hd * 8);
  f4 sa = s4[0], sb = s4[1], da = d4[0], db = d4[1];
  As[idx] = h0 * sa.x + h1 * sa.y + h2 * sa.z + h3 * sa.w + h4 * sb.x + h5 * sb.y + h6 * sb.z + h7 * sb.w;
  Ad[idx] = h0 * da.x + h1 * da.y + h2 * da.z + h3 * da.w + h4 * db.x + h5 * db.y + h6 * db.z + h7 * db.w;
}

// ---------------- aggregation: single pass (no max; |e| small), bf16 gather ----------------
// 32 lanes per node (2 nodes/wave), lane owns channels 4l..4l+3 -> head = l>>1.
// exp(e) without max-shift is mathematically identical (softmax shift invariance); e bounded ~|3|.

__global__ __launch_bounds__(256) void k_agg(const unsigned short* __restrict__ Hb, const float* __restrict__ As, const float* __restrict__ Ad,
                                             const int* __restrict__ row_off, const int* __restrict__ col,
                                             const float* __restrict__ bias, float* __restrict__ V) {
  int node = blockIdx.x * 8 + (threadIdx.x >> 5);   // 6250*8 == 50000 exactly
  int l = threadIdx.x & 31;
  int h = l >> 1;
  int e0 = row_off[node], e1 = row_off[node + 1];
  float adh = Ad[node * 16 + h];
  float den = 0.f;
  f4 acc = make_float4(0.f, 0.f, 0.f, 0.f);
  int j = e0;
  for (; j + 2 <= e1; j += 2) {
    int s0 = col[j], s1 = col[j + 1];
    float ea = As[s0 * 16 + h] + adh;
    float eb = As[s1 * 16 + h] + adh;
    uint2 p0 = *(const uint2*)(Hb + (size_t)s0 * 128 + l * 4);
    uint2 p1 = *(const uint2*)(Hb + (size_t)s1 * 128 + l * 4);
    ea = (ea > 0.f) ? ea : 0.2f * ea;
    eb = (eb > 0.f) ? eb : 0.2f * eb;
    float xa = __expf(ea), xb = __expf(eb);
    den += xa + xb;
    acc.x += xa * b2f(p0.x & 0xffff) + xb * b2f(p1.x & 0xffff);
    acc.y += xa * b2f(p0.x >> 16)    + xb * b2f(p1.x >> 16);
    acc.z += xa * b2f(p0.y & 0xffff) + xb * b2f(p1.y & 0xffff);
    acc.w += xa * b2f(p0.y >> 16)    + xb * b2f(p1.y >> 16);
  }
  if (j < e1) {
    int s0 = col[j];
    float ea = As[s0 * 16 + h] + adh;
    uint2 p0 = *(const uint2*)(Hb + (size_t)s0 * 128 + l * 4);
    ea = (ea > 0.f) ? ea : 0.2f * ea;
    float xa = __expf(ea);
    den += xa;
    acc.x += xa * b2f(p0.x & 0xffff);
    acc.y += xa * b2f(p0.x >> 16);
    acc.z += xa * b2f(p0.y & 0xffff);
    acc.w += xa * b2f(p0.y >> 16);
  }
  float inv = 1.f / (den + 1e-16f);
  f4 bb = *(const f4*)(bias + l * 4);
  f4 o;
  o.x = acc.x * inv + bb.x;
  o.y = acc.y * inv + bb.y;
  o.z = acc.z * inv + bb.z;
  o.w = acc.w * inv + bb.w;
  *(f4*)(V + (size_t)node * 128 + l * 4) = o;
}

// ---------------- BatchNorm (training-mode, biased var) + ReLU ----------------

__global__ __launch_bounds__(256) void k_bnreduce(const float* __restrict__ V, float* __restrict__ acc) {
  int t = threadIdx.x;
  int c = t & 127, half = t >> 7;
  float s = 0.f, s2 = 0.f;
  for (int r = blockIdx.x * 2 + half; r < NN; r += 512) {
    float v = V[(size_t)r * 128 + c];
    s += v; s2 += v * v;
  }
  __shared__ float buf[256];
  buf[t] = s; __syncthreads();
  if (t < 128) atomicAdd(&acc[c], buf[t] + buf[t + 128]);
  __syncthreads();
  buf[t] = s2; __syncthreads();
  if (t < 128) atomicAdd(&acc[128 + c], buf[t] + buf[t + 128]);
}

__global__ __launch_bounds__(128) void k_bnfin(const float* __restrict__ acc, const float* __restrict__ gam,
                                               const float* __restrict__ bet, float* __restrict__ sc) {
  int c = threadIdx.x;
  float mean = acc[c] * (1.f / NN);
  float var = acc[128 + c] * (1.f / NN) - mean * mean;
  var = fmaxf(var, 0.f);
  float s = gam[c] * rsqrtf(var + 1e-5f);
  sc[c] = s;
  sc[128 + c] = bet[c] - mean * s;
}

// BN + ReLU in place on V (fp32) and emit bf16 copy for the next GEMM.
__global__ __launch_bounds__(256) void k_bnapply(float* __restrict__ V, unsigned short* __restrict__ Vb, const float* __restrict__ sc) {
  int idx = blockIdx.x * 256 + threadIdx.x;   // float4 index, total NN*32
  f4* V4 = (f4*)V;
  const f4* sc4 = (const f4*)sc;
  int c4 = idx & 31;
  f4 v = V4[idx];
  f4 s = sc4[c4], sh = sc4[32 + c4];
  v.x = fmaxf(v.x * s.x + sh.x, 0.f);
  v.y = fmaxf(v.y * s.y + sh.y, 0.f);
  v.z = fmaxf(v.z * s.z + sh.z, 0.f);
  v.w = fmaxf(v.w * s.w + sh.w, 0.f);
  V4[idx] = v;
  uint2 o;
  o.x = (unsigned)f2b(v.x) | ((unsigned)f2b(v.y) << 16);
  o.y = (unsigned)f2b(v.z) | ((unsigned)f2b(v.w) << 16);
  ((uint2*)Vb)[idx] = o;
}

// ---------------- pooling + final linear + BN ----------------

__global__ __launch_bounds__(256) void k_pool(const float* __restrict__ V, const int* __restrict__ batch, float* __restrict__ pooled) {
  int t = threadIdx.x;
  int c = t & 127, half = t >> 7;
  int r0 = blockIdx.x * 256;
  int rend = (r0 + 256 < NN) ? (r0 + 256) : NN;
  float s = 0.f; int cur = -1;
  for (int r = r0 + half; r < rend; r += 2) {
    int g = batch[r];
    if (g != cur) {
      if (cur >= 0) atomicAdd(&pooled[cur * 128 + c], s);
      cur = g; s = 0.f;
    }
    s += V[(size_t)r * 128 + c];
  }
  if (cur >= 0) atomicAdd(&pooled[cur * 128 + c], s);
}

__global__ __launch_bounds__(256) void k_cnt(const int* __restrict__ batch, int* __restrict__ gcnt) {
  int i = blockIdx.x * 256 + threadIdx.x;
  if (i < NN) atomicAdd(&gcnt[batch[i]], 1);
}

__global__ __launch_bounds__(256) void k_final(const float* __restrict__ pooled, const int* __restrict__ gcnt,
                                               const float* __restrict__ Wl, const float* __restrict__ bl,
                                               const float* __restrict__ g4, const float* __restrict__ b4,
                                               float* __restrict__ out) {
  int t = threadIdx.x;
  int g = t >> 1, cls = t & 1;
  float cnt = fmaxf((float)gcnt[g], 1.f);
  float inv = 1.f / cnt;
  float z = bl[cls];
  for (int f = 0; f < 128; ++f) {
    float ps = pooled[g * 128 + f];
    z += ps * inv * Wl[f * 2 + cls] + ps * Wl[(128 + f) * 2 + cls];
  }
  __shared__ float zs[256];
  __shared__ float st[4];
  zs[t] = z;
  __syncthreads();
  if (t < 2) {
    float s = 0.f, s2 = 0.f;
    for (int gg = 0; gg < 128; ++gg) { float v = zs[gg * 2 + t]; s += v; s2 += v * v; }
    float mean = s * (1.f / 128.f);
    float var = s2 * (1.f / 128.f) - mean * mean;
    var = fmaxf(var, 0.f);
    float sc = g4[t] * rsqrtf(var + 1e-5f);
    st[t] = sc; st[2 + t] = b4[t] - mean * sc;
  }
  __syncthreads();
  out[t] = zs[t] * st[cls] + st[2 + cls];
}

// ---------------- host launcher ----------------

extern "C" void kernel_launch(void* const* d_in, const int* in_sizes, int n_in,
                              void* d_out, int out_size, void* d_ws, size_t ws_size,
                              hipStream_t stream) {
  const float* x     = (const float*)d_in[0];
  const int*   ei    = (const int*)d_in[1];
  const int*   batch = (const int*)d_in[2];
  const float* W[3]    = {(const float*)d_in[3],  (const float*)d_in[9],  (const float*)d_in[15]};
  const float* bias[3] = {(const float*)d_in[4],  (const float*)d_in[10], (const float*)d_in[16]};
  const float* asrc[3] = {(const float*)d_in[5],  (const float*)d_in[11], (const float*)d_in[17]};
  const float* adst[3] = {(const float*)d_in[6],  (const float*)d_in[12], (const float*)d_in[18]};
  const float* gam[3]  = {(const float*)d_in[7],  (const float*)d_in[13], (const float*)d_in[19]};
  const float* bet[3]  = {(const float*)d_in[8],  (const float*)d_in[14], (const float*)d_in[20]};
  const float* Wl    = (const float*)d_in[21];
  const float* bl    = (const float*)d_in[22];
  const float* g4    = (const float*)d_in[23];
  const float* beta4 = (const float*)d_in[24];

  char* ws = (char*)d_ws;
  size_t off = 0;
  auto alloc = [&](size_t bytes) -> void* {
    void* p = (void*)(ws + off);
    off += (bytes + 255) & ~(size_t)255;
    return p;
  };

  int* counts   = (int*)alloc((size_t)NN * 4);
  int* row_off  = (int*)alloc((size_t)(NN + 1) * 4);
  int* cursor   = (int*)alloc((size_t)NN * 4);
  int* col      = (int*)alloc((size_t)NEP * 4);
  int* blk_tot  = (int*)alloc(256 * 4);
  int* blk_off  = (int*)alloc(256 * 4);
  unsigned short* Xb = (unsigned short*)alloc((size_t)NN * 128 * 2);  // gemm input (layer1: cast(x); then bf16 layer output)
  unsigned short* Hb = (unsigned short*)alloc((size_t)NN * 128 * 2);  // gemm output, bf16
  float* V      = (float*)alloc((size_t)NN * 128 * 4);                // agg / layer output fp32
  float* As     = (float*)alloc((size_t)NN * 16 * 4);
  float* Ad     = (float*)alloc((size_t)NN * 16 * 4);
  unsigned short* Wt0 = (unsigned short*)alloc(16384 * 2);
  unsigned short* Wt1 = (unsigned short*)alloc(16384 * 2);
  unsigned short* Wt2 = (unsigned short*)alloc(16384 * 2);
  const unsigned short* Wt[3] = {Wt0, Wt1, Wt2};
  float* bn_acc = (float*)alloc(256 * 4);
  float* bn_sc  = (float*)alloc(256 * 4);
  float* pooled = (float*)alloc((size_t)(NGRAPH * 128 + NGRAPH) * 4);
  int* gcnt     = (int*)(pooled + NGRAPH * 128);

  // CSR build (identical for all 3 layers)
  hipMemsetAsync(counts, 0, (size_t)NN * 4, stream);
  k_hist<<<(NEP + 255) / 256, 256, 0, stream>>>(ei, counts);
  k_scan1<<<(NN + 255) / 256, 256, 0, stream>>>(counts, row_off, blk_tot);
  k_scan2<<<1, 256, 0, stream>>>(blk_tot, blk_off, row_off, (NN + 255) / 256);
  k_scan3<<<(NN + 255) / 256, 256, 0, stream>>>(row_off, blk_off);
  hipMemcpyAsync(cursor, row_off, (size_t)NN * 4, hipMemcpyDeviceToDevice, stream);
  k_scatter<<<(NEP + 255) / 256, 256, 0, stream>>>(ei, cursor, col);

  // weights -> bf16 transposed; x -> bf16
  k_wt<<<192, 256, 0, stream>>>(W[0], W[1], W[2], Wt0, Wt1, Wt2);
  k_cast<<<(NN * 16 + 255) / 256, 256, 0, stream>>>(x, Xb, NN * 16);

  hipMemsetAsync(pooled, 0, (size_t)(NGRAPH * 128 + NGRAPH) * 4, stream);

  for (int L = 0; L < 3; ++L) {
    k_gemm<<<(NN + 127) / 128, 256, 0, stream>>>(Xb, Wt[L], Hb);
    k_coef<<<(NN * 16) / 256, 256, 0, stream>>>(Hb, asrc[L], adst[L], As, Ad);
    k_agg<<<NN / 8, 256, 0, stream>>>(Hb, As, Ad, row_off, col, bias[L], V);
    hipMemsetAsync(bn_acc, 0, 256 * 4, stream);
    k_bnreduce<<<256, 256, 0, stream>>>(V, bn_acc);
    k_bnfin<<<1, 128, 0, stream>>>(bn_acc, gam[L], bet[L], bn_sc);
    k_bnapply<<<(NN * 32) / 256, 256, 0, stream>>>(V, Xb, bn_sc);   // Xb becomes next layer's bf16 input
  }

  k_pool<<<(NN + 255) / 256, 256, 0, stream>>>(V, batch, pooled);
  k_cnt<<<(NN + 255) / 256, 256, 0, stream>>>(batch, gcnt);
  k_final<<<1, 256, 0, stream>>>(pooled, gcnt, Wl, bl, g4, beta4, (float*)d_out);
}

// Round 3
// 478.441 us; speedup vs baseline: 1.9041x; 1.2716x over previous
//
#include <hip/hip_runtime.h>

#define NN 50000
#define NHEADS 16
#define NGRAPH 128
#define NEDGE 800000
#define NEP (NEDGE + NN)

typedef float4 f4;
typedef __attribute__((ext_vector_type(4))) float f32x4;
typedef __attribute__((ext_vector_type(8))) short s8;   // 8 bf16 (4 VGPRs)

__device__ inline unsigned short f2b(float f) {
  union { float f; unsigned u; } v; v.f = f;
  unsigned r = v.u + 0x7FFFu + ((v.u >> 16) & 1u);   // RNE
  return (unsigned short)(r >> 16);
}
__device__ inline float b2f(unsigned u16) {          // low 16 bits = bf16
  union { unsigned u; float f; } v; v.u = u16 << 16;
  return v.f;
}

// ---------------- CSR build ----------------

__global__ __launch_bounds__(256) void k_hist(const int* __restrict__ ei, int* __restrict__ counts) {
  int i = blockIdx.x * 256 + threadIdx.x;
  if (i >= NEP) return;
  int d = (i < NEDGE) ? ei[NEDGE + i] : (i - NEDGE);
  atomicAdd(&counts[d], 1);
}

__global__ __launch_bounds__(256) void k_scan1(const int* __restrict__ counts, int* __restrict__ row_off, int* __restrict__ blk_tot) {
  __shared__ int buf[256];
  int t = threadIdx.x;
  int i = blockIdx.x * 256 + t;
  int v = (i < NN) ? counts[i] : 0;
  buf[t] = v;
  __syncthreads();
  for (int off = 1; off < 256; off <<= 1) {
    int y = (t >= off) ? buf[t - off] : 0;
    __syncthreads();
    buf[t] += y;
    __syncthreads();
  }
  if (i < NN) row_off[i] = buf[t] - v;
  if (t == 255) blk_tot[blockIdx.x] = buf[255];
}

__global__ __launch_bounds__(256) void k_scan2(const int* __restrict__ blk_tot, int* __restrict__ blk_off, int* __restrict__ row_off, int nb) {
  __shared__ int buf[256];
  int t = threadIdx.x;
  int v = (t < nb) ? blk_tot[t] : 0;
  buf[t] = v;
  __syncthreads();
  for (int off = 1; off < 256; off <<= 1) {
    int y = (t >= off) ? buf[t - off] : 0;
    __syncthreads();
    buf[t] += y;
    __syncthreads();
  }
  if (t < nb) blk_off[t] = buf[t] - v;
  if (t == 255) row_off[NN] = buf[255];
}

__global__ __launch_bounds__(256) void k_scan3(int* __restrict__ row_off, const int* __restrict__ blk_off) {
  int i = blockIdx.x * 256 + threadIdx.x;
  if (i < NN) row_off[i] += blk_off[blockIdx.x];
}

__global__ __launch_bounds__(256) void k_scatter(const int* __restrict__ ei, int* __restrict__ cursor, int* __restrict__ col) {
  int i = blockIdx.x * 256 + threadIdx.x;
  if (i >= NEP) return;
  int s, d;
  if (i < NEDGE) { s = ei[i]; d = ei[NEDGE + i]; }
  else { s = d = i - NEDGE; }
  int pos = atomicAdd(&cursor[d], 1);
  col[pos] = s;
}

// ---------------- fp32 -> bf16 cast (x -> Xb) ----------------

__global__ __launch_bounds__(256) void k_cast(const float* __restrict__ X, unsigned short* __restrict__ Xb, int total8) {
  int i = blockIdx.x * 256 + threadIdx.x;      // 8 elems per thread
  if (i >= total8) return;
  const f4* X4 = (const f4*)X;
  f4 a = X4[2 * i], b = X4[2 * i + 1];
  uint4 o;
  o.x = (unsigned)f2b(a.x) | ((unsigned)f2b(a.y) << 16);
  o.y = (unsigned)f2b(a.z) | ((unsigned)f2b(a.w) << 16);
  o.z = (unsigned)f2b(b.x) | ((unsigned)f2b(b.y) << 16);
  o.w = (unsigned)f2b(b.z) | ((unsigned)f2b(b.w) << 16);
  ((uint4*)Xb)[i] = o;
}

// ---------------- W -> W^T bf16 for all 3 layers ----------------

__global__ __launch_bounds__(256) void k_wt(const float* __restrict__ W0, const float* __restrict__ W1, const float* __restrict__ W2,
                                            unsigned short* __restrict__ T0, unsigned short* __restrict__ T1, unsigned short* __restrict__ T2) {
  int idx = blockIdx.x * 256 + threadIdx.x;    // 3 * 16384
  int L = idx >> 14, r = idx & 16383;
  int n = r >> 7, k = r & 127;
  const float* W = (L == 0) ? W0 : (L == 1) ? W1 : W2;
  unsigned short* T = (L == 0) ? T0 : (L == 1) ? T1 : T2;
  T[n * 128 + k] = f2b(W[k * 128 + n]);
}

// ---------------- GEMM: Hb = bf16( Xb @ W )  via MFMA, no LDS ----------------

__global__ __launch_bounds__(256) void k_gemm(const unsigned short* __restrict__ Xb, const unsigned short* __restrict__ Wt,
                                              unsigned short* __restrict__ Hb) {
  int w = threadIdx.x >> 6, l = threadIdx.x & 63;
  int r0 = blockIdx.x * 128 + w * 32;          // this wave: rows r0..r0+31, all 128 cols
  int lr = l & 15, lg = l >> 4;
  f32x4 acc[2][8];
#pragma unroll
  for (int m = 0; m < 2; ++m)
#pragma unroll
    for (int n = 0; n < 8; ++n) acc[m][n] = (f32x4){0.f, 0.f, 0.f, 0.f};

#pragma unroll
  for (int ks = 0; ks < 4; ++ks) {
    int koff = ks * 32 + lg * 8;
    s8 a[2];
#pragma unroll
    for (int m = 0; m < 2; ++m) {
      int row = r0 + m * 16 + lr;
      row = (row < NN) ? row : (NN - 1);
      a[m] = *(const s8*)(Xb + (size_t)row * 128 + koff);
    }
    s8 b[8];
#pragma unroll
    for (int n = 0; n < 8; ++n)
      b[n] = *(const s8*)(Wt + (size_t)(n * 16 + lr) * 128 + koff);
#pragma unroll
    for (int m = 0; m < 2; ++m)
#pragma unroll
      for (int n = 0; n < 8; ++n)
        acc[m][n] = __builtin_amdgcn_mfma_f32_16x16x32_bf16(a[m], b[n], acc[m][n], 0, 0, 0);
  }

  // C/D layout: col = lane&15, row = (lane>>4)*4 + reg   [verified m89/m91]
#pragma unroll
  for (int m = 0; m < 2; ++m) {
    int rowb = r0 + m * 16 + lg * 4;
#pragma unroll
    for (int n = 0; n < 8; ++n) {
      int colb = n * 16 + lr;
#pragma unroll
      for (int reg = 0; reg < 4; ++reg) {
        int row = rowb + reg;
        if (row < NN) Hb[(size_t)row * 128 + colb] = f2b(acc[m][n][reg]);
      }
    }
  }
}

// ---------------- attention coefficients from bf16 H ----------------

__global__ __launch_bounds__(256) void k_coef(const unsigned short* __restrict__ Hb, const float* __restrict__ asrc,
                                              const float* __restrict__ adst, float* __restrict__ As, float* __restrict__ Ad) {
  int idx = blockIdx.x * 256 + threadIdx.x;
  if (idx >= NN * NHEADS) return;
  int n = idx >> 4, hd = idx & 15;
  uint4 hv = *(const uint4*)(Hb + (size_t)n * 128 + hd * 8);
  float h0 = b2f(hv.x & 0xffff), h1 = b2f(hv.x >> 16);
  float h2 = b2f(hv.y & 0xffff), h3 = b2f(hv.y >> 16);
  float h4 = b2f(hv.z & 0xffff), h5 = b2f(hv.z >> 16);
  float h6 = b2f(hv.w & 0xffff), h7 = b2f(hv.w >> 16);
  const f4* s4 = (const f4*)(asrc + hd * 8);
  const f4* d4 = (const f4*)(adst + hd * 8);
  f4 sa = s4[0], sb = s4[1], da = d4[0], db = d4[1];
  As[idx] = h0 * sa.x + h1 * sa.y + h2 * sa.z + h3 * sa.w + h4 * sb.x + h5 * sb.y + h6 * sb.z + h7 * sb.w;
  Ad[idx] = h0 * da.x + h1 * da.y + h2 * da.z + h3 * da.w + h4 * db.x + h5 * db.y + h6 * db.z + h7 * db.w;
}

// ---------------- aggregation: single pass, 4-deep pipelined bf16 gather ----------------
// 32 lanes per node, lane owns channels 4l..4l+3 -> head = l>>1.
// exp without max-shift: softmax shift-invariant, |e| bounded (~3) so no overflow.

__global__ __launch_bounds__(256) void k_agg(const unsigned short* __restrict__ Hb, const float* __restrict__ As, const float* __restrict__ Ad,
                                             const int* __restrict__ row_off, const int* __restrict__ col,
                                             const float* __restrict__ bias, float* __restrict__ V) {
  int node = blockIdx.x * 8 + (threadIdx.x >> 5);   // 6250*8 == 50000 exactly
  int l = threadIdx.x & 31;
  int h = l >> 1;
  int e0 = row_off[node], e1 = row_off[node + 1];
  float adh = Ad[node * 16 + h];
  float den = 0.f;
  f4 acc = make_float4(0.f, 0.f, 0.f, 0.f);
  int j = e0;
  for (; j + 4 <= e1; j += 4) {
    // issue 4 independent index loads
    int s0 = col[j], s1 = col[j + 1], s2 = col[j + 2], s3 = col[j + 3];
    // issue 4 As + 4 H-row loads before any compute (8 concurrent gathers)
    float a0 = As[s0 * 16 + h], a1 = As[s1 * 16 + h], a2 = As[s2 * 16 + h], a3 = As[s3 * 16 + h];
    uint2 p0 = *(const uint2*)(Hb + (size_t)s0 * 128 + l * 4);
    uint2 p1 = *(const uint2*)(Hb + (size_t)s1 * 128 + l * 4);
    uint2 p2 = *(const uint2*)(Hb + (size_t)s2 * 128 + l * 4);
    uint2 p3 = *(const uint2*)(Hb + (size_t)s3 * 128 + l * 4);
    a0 += adh; a1 += adh; a2 += adh; a3 += adh;
    a0 = (a0 > 0.f) ? a0 : 0.2f * a0;
    a1 = (a1 > 0.f) ? a1 : 0.2f * a1;
    a2 = (a2 > 0.f) ? a2 : 0.2f * a2;
    a3 = (a3 > 0.f) ? a3 : 0.2f * a3;
    float x0 = __expf(a0), x1 = __expf(a1), x2 = __expf(a2), x3 = __expf(a3);
    den += (x0 + x1) + (x2 + x3);
    acc.x += x0 * b2f(p0.x & 0xffff) + x1 * b2f(p1.x & 0xffff) + x2 * b2f(p2.x & 0xffff) + x3 * b2f(p3.x & 0xffff);
    acc.y += x0 * b2f(p0.x >> 16)    + x1 * b2f(p1.x >> 16)    + x2 * b2f(p2.x >> 16)    + x3 * b2f(p3.x >> 16);
    acc.z += x0 * b2f(p0.y & 0xffff) + x1 * b2f(p1.y & 0xffff) + x2 * b2f(p2.y & 0xffff) + x3 * b2f(p3.y & 0xffff);
    acc.w += x0 * b2f(p0.y >> 16)    + x1 * b2f(p1.y >> 16)    + x2 * b2f(p2.y >> 16)    + x3 * b2f(p3.y >> 16);
  }
  for (; j < e1; ++j) {
    int s0 = col[j];
    float a0 = As[s0 * 16 + h] + adh;
    uint2 p0 = *(const uint2*)(Hb + (size_t)s0 * 128 + l * 4);
    a0 = (a0 > 0.f) ? a0 : 0.2f * a0;
    float x0 = __expf(a0);
    den += x0;
    acc.x += x0 * b2f(p0.x & 0xffff);
    acc.y += x0 * b2f(p0.x >> 16);
    acc.z += x0 * b2f(p0.y & 0xffff);
    acc.w += x0 * b2f(p0.y >> 16);
  }
  float inv = 1.f / (den + 1e-16f);
  f4 bb = *(const f4*)(bias + l * 4);
  f4 o;
  o.x = acc.x * inv + bb.x;
  o.y = acc.y * inv + bb.y;
  o.z = acc.z * inv + bb.z;
  o.w = acc.w * inv + bb.w;
  *(f4*)(V + (size_t)node * 128 + l * 4) = o;
}

// ---------------- BatchNorm (training-mode, biased var) + ReLU ----------------

__global__ __launch_bounds__(256) void k_bnreduce(const float* __restrict__ V, float* __restrict__ acc) {
  int t = threadIdx.x;
  int c = t & 127, half = t >> 7;
  float s = 0.f, s2 = 0.f;
  for (int r = blockIdx.x * 2 + half; r < NN; r += 512) {
    float v = V[(size_t)r * 128 + c];
    s += v; s2 += v * v;
  }
  __shared__ float buf[256];
  buf[t] = s; __syncthreads();
  if (t < 128) atomicAdd(&acc[c], buf[t] + buf[t + 128]);
  __syncthreads();
  buf[t] = s2; __syncthreads();
  if (t < 128) atomicAdd(&acc[128 + c], buf[t] + buf[t + 128]);
}

__global__ __launch_bounds__(128) void k_bnfin(const float* __restrict__ acc, const float* __restrict__ gam,
                                               const float* __restrict__ bet, float* __restrict__ sc) {
  int c = threadIdx.x;
  float mean = acc[c] * (1.f / NN);
  float var = acc[128 + c] * (1.f / NN) - mean * mean;
  var = fmaxf(var, 0.f);
  float s = gam[c] * rsqrtf(var + 1e-5f);
  sc[c] = s;
  sc[128 + c] = bet[c] - mean * s;
}

// BN + ReLU in place on V (fp32) and emit bf16 copy for the next GEMM.
__global__ __launch_bounds__(256) void k_bnapply(float* __restrict__ V, unsigned short* __restrict__ Vb, const float* __restrict__ sc) {
  int idx = blockIdx.x * 256 + threadIdx.x;   // float4 index, total NN*32
  f4* V4 = (f4*)V;
  const f4* sc4 = (const f4*)sc;
  int c4 = idx & 31;
  f4 v = V4[idx];
  f4 s = sc4[c4], sh = sc4[32 + c4];
  v.x = fmaxf(v.x * s.x + sh.x, 0.f);
  v.y = fmaxf(v.y * s.y + sh.y, 0.f);
  v.z = fmaxf(v.z * s.z + sh.z, 0.f);
  v.w = fmaxf(v.w * s.w + sh.w, 0.f);
  V4[idx] = v;
  uint2 o;
  o.x = (unsigned)f2b(v.x) | ((unsigned)f2b(v.y) << 16);
  o.y = (unsigned)f2b(v.z) | ((unsigned)f2b(v.w) << 16);
  ((uint2*)Vb)[idx] = o;
}

// ---------------- pooling + final linear + BN ----------------

__global__ __launch_bounds__(256) void k_pool(const float* __restrict__ V, const int* __restrict__ batch, float* __restrict__ pooled) {
  int t = threadIdx.x;
  int c = t & 127, half = t >> 7;
  int r0 = blockIdx.x * 256;
  int rend = (r0 + 256 < NN) ? (r0 + 256) : NN;
  float s = 0.f; int cur = -1;
  for (int r = r0 + half; r < rend; r += 2) {
    int g = batch[r];
    if (g != cur) {
      if (cur >= 0) atomicAdd(&pooled[cur * 128 + c], s);
      cur = g; s = 0.f;
    }
    s += V[(size_t)r * 128 + c];
  }
  if (cur >= 0) atomicAdd(&pooled[cur * 128 + c], s);
}

// counts via binary search on sorted batch — no atomics
__global__ __launch_bounds__(128) void k_cnt(const int* __restrict__ batch, int* __restrict__ gcnt) {
  int g = threadIdx.x;
  int lo = 0, hi = NN;
  while (lo < hi) { int mid = (lo + hi) >> 1; if (batch[mid] < g) lo = mid + 1; else hi = mid; }
  int a = lo;
  lo = 0; hi = NN;
  while (lo < hi) { int mid = (lo + hi) >> 1; if (batch[mid] < g + 1) lo = mid + 1; else hi = mid; }
  gcnt[g] = lo - a;
}

__global__ __launch_bounds__(256) void k_final(const float* __restrict__ pooled, const int* __restrict__ gcnt,
                                               const float* __restrict__ Wl, const float* __restrict__ bl,
                                               const float* __restrict__ g4, const float* __restrict__ b4,
                                               float* __restrict__ out) {
  int t = threadIdx.x;
  int g = t >> 1, cls = t & 1;
  float cnt = fmaxf((float)gcnt[g], 1.f);
  float inv = 1.f / cnt;
  float z = bl[cls];
  for (int f = 0; f < 128; ++f) {
    float ps = pooled[g * 128 + f];
    z += ps * inv * Wl[f * 2 + cls] + ps * Wl[(128 + f) * 2 + cls];
  }
  __shared__ float zs[256];
  __shared__ float st[4];
  zs[t] = z;
  __syncthreads();
  if (t < 2) {
    float s = 0.f, s2 = 0.f;
    for (int gg = 0; gg < 128; ++gg) { float v = zs[gg * 2 + t]; s += v; s2 += v * v; }
    float mean = s * (1.f / 128.f);
    float var = s2 * (1.f / 128.f) - mean * mean;
    var = fmaxf(var, 0.f);
    float sc = g4[t] * rsqrtf(var + 1e-5f);
    st[t] = sc; st[2 + t] = b4[t] - mean * sc;
  }
  __syncthreads();
  out[t] = zs[t] * st[cls] + st[2 + cls];
}

// ---------------- host launcher ----------------

extern "C" void kernel_launch(void* const* d_in, const int* in_sizes, int n_in,
                              void* d_out, int out_size, void* d_ws, size_t ws_size,
                              hipStream_t stream) {
  const float* x     = (const float*)d_in[0];
  const int*   ei    = (const int*)d_in[1];
  const int*   batch = (const int*)d_in[2];
  const float* W[3]    = {(const float*)d_in[3],  (const float*)d_in[9],  (const float*)d_in[15]};
  const float* bias[3] = {(const float*)d_in[4],  (const float*)d_in[10], (const float*)d_in[16]};
  const float* asrc[3] = {(const float*)d_in[5],  (const float*)d_in[11], (const float*)d_in[17]};
  const float* adst[3] = {(const float*)d_in[6],  (const float*)d_in[12], (const float*)d_in[18]};
  const float* gam[3]  = {(const float*)d_in[7],  (const float*)d_in[13], (const float*)d_in[19]};
  const float* bet[3]  = {(const float*)d_in[8],  (const float*)d_in[14], (const float*)d_in[20]};
  const float* Wl    = (const float*)d_in[21];
  const float* bl    = (const float*)d_in[22];
  const float* g4    = (const float*)d_in[23];
  const float* beta4 = (const float*)d_in[24];

  char* ws = (char*)d_ws;
  size_t off = 0;
  auto alloc = [&](size_t bytes) -> void* {
    void* p = (void*)(ws + off);
    off += (bytes + 255) & ~(size_t)255;
    return p;
  };

  int* counts   = (int*)alloc((size_t)NN * 4);
  int* row_off  = (int*)alloc((size_t)(NN + 1) * 4);
  int* cursor   = (int*)alloc((size_t)NN * 4);
  int* col      = (int*)alloc((size_t)NEP * 4);
  int* blk_tot  = (int*)alloc(256 * 4);
  int* blk_off  = (int*)alloc(256 * 4);
  unsigned short* Xb = (unsigned short*)alloc((size_t)NN * 128 * 2);
  unsigned short* Hb = (unsigned short*)alloc((size_t)NN * 128 * 2);
  float* V      = (float*)alloc((size_t)NN * 128 * 4);
  float* As     = (float*)alloc((size_t)NN * 16 * 4);
  float* Ad     = (float*)alloc((size_t)NN * 16 * 4);
  unsigned short* Wt0 = (unsigned short*)alloc(16384 * 2);
  unsigned short* Wt1 = (unsigned short*)alloc(16384 * 2);
  unsigned short* Wt2 = (unsigned short*)alloc(16384 * 2);
  const unsigned short* Wt[3] = {Wt0, Wt1, Wt2};
  float* bn_acc = (float*)alloc(256 * 4);
  float* bn_sc  = (float*)alloc(256 * 4);
  float* pooled = (float*)alloc((size_t)(NGRAPH * 128 + NGRAPH) * 4);
  int* gcnt     = (int*)(pooled + NGRAPH * 128);

  // CSR build (identical for all 3 layers)
  hipMemsetAsync(counts, 0, (size_t)NN * 4, stream);
  k_hist<<<(NEP + 255) / 256, 256, 0, stream>>>(ei, counts);
  k_scan1<<<(NN + 255) / 256, 256, 0, stream>>>(counts, row_off, blk_tot);
  k_scan2<<<1, 256, 0, stream>>>(blk_tot, blk_off, row_off, (NN + 255) / 256);
  k_scan3<<<(NN + 255) / 256, 256, 0, stream>>>(row_off, blk_off);
  hipMemcpyAsync(cursor, row_off, (size_t)NN * 4, hipMemcpyDeviceToDevice, stream);
  k_scatter<<<(NEP + 255) / 256, 256, 0, stream>>>(ei, cursor, col);

  // weights -> bf16 transposed; x -> bf16
  k_wt<<<192, 256, 0, stream>>>(W[0], W[1], W[2], Wt0, Wt1, Wt2);
  k_cast<<<(NN * 16 + 255) / 256, 256, 0, stream>>>(x, Xb, NN * 16);

  hipMemsetAsync(pooled, 0, (size_t)(NGRAPH * 128 + NGRAPH) * 4, stream);

  for (int L = 0; L < 3; ++L) {
    k_gemm<<<(NN + 127) / 128, 256, 0, stream>>>(Xb, Wt[L], Hb);
    k_coef<<<(NN * 16) / 256, 256, 0, stream>>>(Hb, asrc[L], adst[L], As, Ad);
    k_agg<<<NN / 8, 256, 0, stream>>>(Hb, As, Ad, row_off, col, bias[L], V);
    hipMemsetAsync(bn_acc, 0, 256 * 4, stream);
    k_bnreduce<<<256, 256, 0, stream>>>(V, bn_acc);
    k_bnfin<<<1, 128, 0, stream>>>(bn_acc, gam[L], bet[L], bn_sc);
    k_bnapply<<<(NN * 32) / 256, 256, 0, stream>>>(V, Xb, bn_sc);   // Xb becomes next layer's bf16 input
  }

  k_pool<<<(NN + 255) / 256, 256, 0, stream>>>(V, batch, pooled);
  k_cnt<<<1, 128, 0, stream>>>(batch, gcnt);
  k_final<<<1, 256, 0, stream>>>(pooled, gcnt, Wl, bl, g4, beta4, (float*)d_out);
}